// Round 5
// baseline (307.694 us; speedup 1.0000x reference)
//
#include <hip/hip_runtime.h>
#include <cstdint>
#include <cstddef>

// EEG_SimpleLSM round 11: revert asm loader (R10 FAILED, absmax 5.28) +
// spill-kill + setprio.
// R10 root-cause: inline-asm global_load destinations (vr[8], 32 VGPRs live
// across the whole phase loop) + pre-existing scratch pressure (R9's
// WRITE_SIZE jumped 128KB->2.9MB = spill traffic). Spilling an async-pending
// asm-load dest is incorrect on CDNA: no per-VGPR scoreboard; the spill
// store reads the register before the load lands. Also R10's premise (a)
// was weak: the loader's vmcnt drain lands ~600cy after issue inside a
// ~6000cy phase — not critical-path. The R9 SPILL itself (scratch VMEM
// round trips inside L0u/L1u carried loops) is the better suspect for the
// unmodeled stall.
// R11:
//  (1) Loader back to compiler-visible loads (correct by construction):
//      8 back-to-back dwordx4 loads -> regs -> 8 b128 LDS writes, write
//      masked by exec (if(ok)) instead of per-element cndmask.
//  (2) Keep R10's de-spilled 8-step L0u (C0/C1+N0/N1, one packed b128
//      write) and depth-8 gather rotation in L1u/L2 (<=10 outstanding DS
//      ops, exactly lgkm-encodable). Live sets <= ~30 regs per stage.
//  (3) T5: s_setprio(1) around the three heavy update inner loops — waves
//      are role-split (the regime where setprio pays, per guide m218b).
// Watch counter: WRITE_SIZE must return to ~0.13MB (spill gone). dur
// prediction 130-150us if the scratch round-trips were on-path.
// Waves (512 thr): w4 loader(p) | w0 L0u(p-1) | w1 L0r(p-2) | w2 L1u(p-3)
// | w3/w6 L1r lo/hi(p-4) | w5/w7 L2 halves(p-5). Depth-5 pipeline,
// double-buffered rings, one __syncthreads per phase (wave-uniform
// branches). Arithmetic identical to R9/R10 (absmax 0.0): carried-select
// folding, Markstein exact f32 /3, zero-column gather, reciprocal-mul
// /80000.

#pragma clang fp contract(off)

typedef float f32x4 __attribute__((ext_vector_type(4)));

constexpr int T_TOTAL = 4000;
constexpr int NCH = 32;
constexpr int N1 = 64;
constexpr int N2 = 128;
constexpr int CT = 64;
constexpr int TS0 = 92;                           // xs [ch][t] stride
constexpr int TS1 = 76;                           // nv rings [n][t] stride
constexpr int NCHUNK = (T_TOTAL + CT - 1) / CT;   // 63 (last chunk = 32 steps)

__device__ __forceinline__ int read_lane_i(int v, int l) {
  return __builtin_amdgcn_readlane(v, l);
}

__global__ __launch_bounds__(512, 1) void lsm_kernel(
    const float* __restrict__ x, const float* __restrict__ W1,
    const float* __restrict__ W2, float* __restrict__ out) {
  __shared__ float w1s[N1 * 33];        // W1[n][k] at n*33+k; col 32 == 0
  __shared__ float w2s[N2 * 65];        // W2[n][k] at n*65+k; col 64 == 0
  __shared__ float xs[2][NCH * TS0];    // x chunk, [ch][t]
  __shared__ float nv0r[2][NCH * TS1];  // L0 nv ring, [neuron][t]
  __shared__ float nv1r[2][N1 * TS1];   // L1 nv ring, [neuron][t]
  __shared__ unsigned j0r[2][CT];       // L0 gather idx (32 = zero col)
  __shared__ float mpr[2][2][CT];       // L1 partial max  [parity][half][step]
  __shared__ int   jpr[2][2][CT];       // L1 partial argj [parity][half][step]

  const int tid = threadIdx.x;
  const int wid = tid >> 6;
  const int lane = tid & 63;
  const int b = blockIdx.x;

  for (int e = tid; e < N1 * NCH; e += 512) w1s[(e >> 5) * 33 + (e & 31)] = W1[e];
  for (int e = tid; e < N2 * N1; e += 512) w2s[(e >> 6) * 65 + (e & 63)] = W2[e];
  if (tid < N1) w1s[tid * 33 + 32] = 0.f;          // zero column
  if (tid < N2) w2s[tid * 65 + 64] = 0.f;          // zero column
  __syncthreads();

  const float* xb = x + (size_t)b * (NCH * T_TOTAL);
  constexpr float R3 = 1.0f / 3.0f;                // RN(1/3)
  constexpr float R80 = 1.0f / 80000.0f;

  // Persistent per-wave state: pre-reset membranes.
  float nv0p = 0.f;                  // w0
  float nv1p = 0.f;                  // w2
  float nv2p = 0.f;                  // w5 (rows 0-63) / w7 (rows 64-127)

  for (int p = 0; p < NCHUNK + 5; ++p) {
    if (wid == 0) {
      // ---------- L0 update (chunk p-1): the carried chain ----------
      const int c = p - 1;
      if (c >= 0 && c < NCHUNK) {
        const int S = min(CT, T_TOTAL - c * CT);
        const int xl = lane & 31;                  // lanes 32-63 mirror 0-31
        const int hi4 = (lane >> 5) << 2;          // 0 | 4: write-half offset
        const float* xrow = xs[c & 1] + xl * TS0;  // mirror lanes: broadcast
        float* nrow = nv0r[c & 1] + xl * TS1 + hi4;
        f32x4 C0 = *(const f32x4*)(xrow + 0);
        f32x4 C1 = *(const f32x4*)(xrow + 4);
        __builtin_amdgcn_s_setprio(1);
        for (int tb = 0; tb < S; tb += 8) {
          f32x4 N0 = *(const f32x4*)(xrow + tb + 8);   // pad-safe (TS0=92)
          f32x4 Nx = *(const f32x4*)(xrow + tb + 12);
          float nva[8];
#pragma unroll
          for (int k = 0; k < 8; ++k) {
            float xc = (k < 4) ? C0[k] : C1[k - 4];
            float a  = nv0p + xc;
            float q0 = nv0p * R3;
            float e  = __builtin_fmaf(-3.0f, q0, nv0p);
            float q  = __builtin_fmaf(e, R3, q0);  // == RN(nv0p/3)
            bool  r  = nv0p >= 1.5f;
            float f  = a - q;
            nv0p = r ? xc : f;
            nva[k] = nv0p;
          }
          f32x4 wv;
          wv.x = hi4 ? nva[4] : nva[0];
          wv.y = hi4 ? nva[5] : nva[1];
          wv.z = hi4 ? nva[6] : nva[2];
          wv.w = hi4 ? nva[7] : nva[3];
          *(f32x4*)(nrow + tb) = wv;    // lane l & l+32 cover steps tb..tb+7
          C0 = N0; C1 = Nx;
        }
        __builtin_amdgcn_s_setprio(0);
      }
    } else if (wid == 1) {
      // ---------- L0 reduce (chunk p-2): lane = step, scan 32 neurons ----
      const int c = p - 2;
      if (c >= 0 && c < NCHUNK) {
        const float* nvs = nv0r[c & 1] + lane;     // [n][t]: lane-contiguous
        float m = nvs[0];
        int j = 0;
#pragma unroll 8
        for (int n = 1; n < 32; ++n) {
          float v = nvs[n * TS1];
          bool g = v > m;               // strict: first index kept on ties
          j = g ? n : j;
          m = g ? v : m;
        }
        // lanes >= S read stale rows: finite, bounded j, never consumed.
        j0r[c & 1][lane] = (m >= 1.5f) ? (unsigned)j : 32u;  // 32 -> zero col
      }
    } else if (wid == 2) {
      // ---------- L1 update (chunk p-3): depth-8 gather rotation ----------
      const int c = p - 3;
      if (c >= 0 && c < NCHUNK) {
        const int S = min(CT, T_TOTAL - c * CT);
        const int jv = (int)j0r[c & 1][lane];
        const float* wrow = w1s + lane * 33;
        float* nrow = nv1r[c & 1] + lane * TS1;
        float hr[8];
#pragma unroll
        for (int k = 0; k < 8; ++k) hr[k] = wrow[read_lane_i(jv, k)];
        __builtin_amdgcn_s_setprio(1);
        for (int tb = 0; tb < S; tb += 8) {
          float nva[8];
#pragma unroll
          for (int k = 0; k < 8; ++k) {
            float h = hr[k];
            hr[k] = wrow[read_lane_i(jv, (tb + k + 8) & 63)];  // wrap: dead
            float a = nv1p + h;
            float m = nv1p * R80;
            bool  r = nv1p >= 1.2f;
            float f = a - m;
            nv1p = r ? h : f;
            nva[k] = nv1p;
          }
          f32x4 w0v = {nva[0], nva[1], nva[2], nva[3]};
          f32x4 w1v = {nva[4], nva[5], nva[6], nva[7]};
          *(f32x4*)(nrow + tb) = w0v;
          *(f32x4*)(nrow + tb + 4) = w1v;
        }
        __builtin_amdgcn_s_setprio(0);
      }
    } else if (wid == 3 || wid == 6) {
      // ---------- L1 reduce (chunk p-4): lane = step, neuron half-scan ----
      const int c = p - 4;
      if (c >= 0 && c < NCHUNK) {
        const int half = (wid == 6) ? 1 : 0;
        const float* nvs = nv1r[c & 1] + half * 32 * TS1 + lane;
        float m = nvs[0];
        int j = 0;
#pragma unroll 8
        for (int n = 1; n < 32; ++n) {
          float v = nvs[n * TS1];
          bool g = v > m;
          j = g ? n : j;
          m = g ? v : m;
        }
        mpr[c & 1][half][lane] = m;
        jpr[c & 1][half][lane] = j;
      }
    } else if (wid == 4) {
      // ---------- loader: x chunk p -> xs [ch][t], dwordx4 in+out ----------
      const int c = p;
      if (c < NCHUNK) {
        float* dst = xs[c & 1];
        const int g4 = lane >> 4;            // channel sub-index 0..3
        const int tl = (lane & 15) << 2;     // local t: 0,4,...,60
        const int tg = c * CT + tl;          // global t of first element
        const bool ok = (tg + 3) < T_TOTAL;  // all-4 valid (T_TOTAL % 4 == 0)
        const int tgs = ok ? tg : 0;         // clamped, always in-bounds
        f32x4 vr[8];
        // Phase A: 8 independent 16B loads, back-to-back in flight; the
        // single round trip overlaps the rest of this phase (~6k cyc).
#pragma unroll
        for (int g = 0; g < 8; ++g) {
          const int k = g * 4 + g4;
          vr[g] = *reinterpret_cast<const f32x4*>(&xb[(size_t)k * T_TOTAL + tgs]);
        }
        // Phase B: 8 ds_write_b128 under exec mask; rows with !ok keep stale
        // bits, only ever touched by L0u's dead prefetch (never consumed).
        if (ok) {
#pragma unroll
          for (int g = 0; g < 8; ++g) {
            const int k = g * 4 + g4;
            *(f32x4*)(&dst[k * TS0 + tl]) = vr[g];
          }
        }
      }
    } else {
      // ---------- L2 update (chunk p-5): w5 rows 0-63, w7 rows 64-127 ----
      const int c = p - 5;
      if (c >= 0 && c < NCHUNK) {
        const int S = min(CT, T_TOTAL - c * CT);
        // merge L1 partials per-lane (lane = step); tie -> low half = first idx
        float mlo = mpr[c & 1][0][lane], mhi = mpr[c & 1][1][lane];
        int jlo = jpr[c & 1][0][lane], jhi = jpr[c & 1][1][lane];
        bool g = mhi > mlo;
        float mm = g ? mhi : mlo;
        int jj = g ? (jhi + 32) : jlo;
        const int pkv = (mm >= 1.2f) ? jj : 64;          // 64 -> zero col
        const float* wrow = w2s + (lane + ((wid == 7) ? 64 : 0)) * 65;
        float hr[8];
#pragma unroll
        for (int k = 0; k < 8; ++k) hr[k] = wrow[read_lane_i(pkv, k)];
        __builtin_amdgcn_s_setprio(1);
        for (int tb = 0; tb < S; tb += 8) {
#pragma unroll
          for (int k = 0; k < 8; ++k) {
            float h = hr[k];
            hr[k] = wrow[read_lane_i(pkv, (tb + k + 8) & 63)];  // wrap: dead
            float a = nv2p + h;
            float m = nv2p * R80;
            bool  r = nv2p >= 1.2f;
            float f = a - m;
            nv2p = r ? h : f;
          }
        }
        __builtin_amdgcn_s_setprio(0);
      }
    }
    __syncthreads();  // wave-uniform branches: all 8 waves always arrive
  }

  // nv2p is the pre-reset membrane of the last step == pre_v2.
  if (wid == 5) out[(size_t)b * N2 + lane] = expf(nv2p);
  if (wid == 7) out[(size_t)b * N2 + 64 + lane] = expf(nv2p);
}

extern "C" void kernel_launch(void* const* d_in, const int* in_sizes, int n_in,
                              void* d_out, int out_size, void* d_ws, size_t ws_size,
                              hipStream_t stream) {
  (void)n_in; (void)out_size; (void)d_ws; (void)ws_size;
  const float* x = (const float*)d_in[0];
  const float* W1 = (const float*)d_in[1];
  const float* W2 = (const float*)d_in[2];
  float* out = (float*)d_out;
  const int B = in_sizes[0] / (NCH * T_TOTAL);  // 256
  lsm_kernel<<<dim3(B), dim3(512), 0, stream>>>(x, W1, W2, out);
}

// Round 6
// 277.690 us; speedup vs baseline: 1.1080x; 1.1080x over previous
//
#include <hip/hip_runtime.h>
#include <cstdint>
#include <cstddef>

// EEG_SimpleLSM round 12: CT 64->96 — amortize per-phase fixed overhead.
// R11 post-mortem: WRITE_SIZE 2.9MB->128KB (spill killed) but dur flat
// 171->176us -> spill was off-path; setprio null-to-negative (lockstep
// barrier regime, m190) -> dropped. Model audit: phase = 6.2k cyc but the
// worst stage models at ~2k; VALUBusy's 42% is a gfx94x-formula artifact
// (assumes 4 issue-cyc/wave64 op; CDNA4 SIMD-32 = 2) -> real VALU occupancy
// ~21%, matching instruction hand-count. Residual ~4.2k cyc/phase is fixed
// overhead (barrier skew, stage-entry LDS turnaround, drains), paid 68x,
// insensitive to all R9-R11 stage-body edits.
// R12: CT=96 -> phases 68->47: predict 47*(4.2k+1.5*2.0k) ~= 338k cyc ~=
// 141us. If flat, fixed-overhead theory is falsified (overhead is
// step-proportional) — decisive either way.
// Mechanics: reduces do full-wave pass (steps 0-63) + lane<32 masked pass
// (steps 64-95); gather rotation selects jv/jv2 block-uniformly (8-aligned
// blocks never straddle 64); loader = 12 dwordx4/lane over 8ch x 8lane
// groups (128B contiguous segments); TS0=108, TS1=100 (both ==4|12 mod 32
// -> minimum-time b128 bank pattern, same class as measured-0-conflict 76).
// LDS 149.5KB <= 160KB, still 1 block/CU.
// Waves (512 thr): w4 loader(p) | w0 L0u(p-1) | w1 L0r(p-2) | w2 L1u(p-3)
// | w3/w6 L1r lo/hi(p-4) | w5/w7 L2 halves(p-5). Depth-5 pipeline,
// double-buffered rings, one __syncthreads per phase (wave-uniform
// branches). Arithmetic identical to R9-R11 (absmax 0.0): carried-select
// folding, Markstein exact f32 /3, zero-column gather, reciprocal-mul
// /80000.

#pragma clang fp contract(off)

typedef float f32x4 __attribute__((ext_vector_type(4)));

constexpr int T_TOTAL = 4000;
constexpr int NCH = 32;
constexpr int N1 = 64;
constexpr int N2 = 128;
constexpr int CT = 96;
constexpr int TS0 = 108;                          // xs [ch][t] stride
constexpr int TS1 = 100;                          // nv rings [n][t] stride
constexpr int NCHUNK = (T_TOTAL + CT - 1) / CT;   // 42 (last chunk = 64 steps)

__device__ __forceinline__ int read_lane_i(int v, int l) {
  return __builtin_amdgcn_readlane(v, l);
}

__global__ __launch_bounds__(512, 1) void lsm_kernel(
    const float* __restrict__ x, const float* __restrict__ W1,
    const float* __restrict__ W2, float* __restrict__ out) {
  __shared__ float w1s[N1 * 33];        // W1[n][k] at n*33+k; col 32 == 0
  __shared__ float w2s[N2 * 65];        // W2[n][k] at n*65+k; col 64 == 0
  __shared__ float xs[2][NCH * TS0];    // x chunk, [ch][t]
  __shared__ float nv0r[2][NCH * TS1];  // L0 nv ring, [neuron][t]
  __shared__ float nv1r[2][N1 * TS1];   // L1 nv ring, [neuron][t]
  __shared__ unsigned j0r[2][CT];       // L0 gather idx (32 = zero col)
  __shared__ float mpr[2][2][CT];       // L1 partial max  [parity][half][step]
  __shared__ int   jpr[2][2][CT];       // L1 partial argj [parity][half][step]

  const int tid = threadIdx.x;
  const int wid = tid >> 6;
  const int lane = tid & 63;
  const int b = blockIdx.x;

  for (int e = tid; e < N1 * NCH; e += 512) w1s[(e >> 5) * 33 + (e & 31)] = W1[e];
  for (int e = tid; e < N2 * N1; e += 512) w2s[(e >> 6) * 65 + (e & 63)] = W2[e];
  if (tid < N1) w1s[tid * 33 + 32] = 0.f;          // zero column
  if (tid < N2) w2s[tid * 65 + 64] = 0.f;          // zero column
  __syncthreads();

  const float* xb = x + (size_t)b * (NCH * T_TOTAL);
  constexpr float R3 = 1.0f / 3.0f;                // RN(1/3)
  constexpr float R80 = 1.0f / 80000.0f;

  // Persistent per-wave state: pre-reset membranes.
  float nv0p = 0.f;                  // w0
  float nv1p = 0.f;                  // w2
  float nv2p = 0.f;                  // w5 (rows 0-63) / w7 (rows 64-127)

  for (int p = 0; p < NCHUNK + 5; ++p) {
    if (wid == 0) {
      // ---------- L0 update (chunk p-1): the carried chain ----------
      const int c = p - 1;
      if (c >= 0 && c < NCHUNK) {
        const int S = min(CT, T_TOTAL - c * CT);
        const int xl = lane & 31;                  // lanes 32-63 mirror 0-31
        const int hi4 = (lane >> 5) << 2;          // 0 | 4: write-half offset
        const float* xrow = xs[c & 1] + xl * TS0;  // mirror lanes: broadcast
        float* nrow = nv0r[c & 1] + xl * TS1 + hi4;
        f32x4 C0 = *(const f32x4*)(xrow + 0);
        f32x4 C1 = *(const f32x4*)(xrow + 4);
        for (int tb = 0; tb < S; tb += 8) {
          f32x4 N0 = *(const f32x4*)(xrow + tb + 8);   // pad-safe (TS0=108)
          f32x4 Nx = *(const f32x4*)(xrow + tb + 12);
          float nva[8];
#pragma unroll
          for (int k = 0; k < 8; ++k) {
            float xc = (k < 4) ? C0[k] : C1[k - 4];
            float a  = nv0p + xc;
            float q0 = nv0p * R3;
            float e  = __builtin_fmaf(-3.0f, q0, nv0p);
            float q  = __builtin_fmaf(e, R3, q0);  // == RN(nv0p/3)
            bool  r  = nv0p >= 1.5f;
            float f  = a - q;
            nv0p = r ? xc : f;
            nva[k] = nv0p;
          }
          f32x4 wv;
          wv.x = hi4 ? nva[4] : nva[0];
          wv.y = hi4 ? nva[5] : nva[1];
          wv.z = hi4 ? nva[6] : nva[2];
          wv.w = hi4 ? nva[7] : nva[3];
          *(f32x4*)(nrow + tb) = wv;    // lane l & l+32 cover steps tb..tb+7
          C0 = N0; C1 = Nx;
        }
      }
    } else if (wid == 1) {
      // ---------- L0 reduce (chunk p-2): lane = step, scan 32 neurons ----
      const int c = p - 2;
      if (c >= 0 && c < NCHUNK) {
        const int cb = c & 1;
        const float* nvs = nv0r[cb] + lane;        // [n][t]: lane-contiguous
        float m = nvs[0];
        int j = 0;
#pragma unroll 8
        for (int n = 1; n < 32; ++n) {
          float v = nvs[n * TS1];
          bool g = v > m;               // strict: first index kept on ties
          j = g ? n : j;
          m = g ? v : m;
        }
        // lanes/steps >= S read stale rows: finite, bounded j, never used.
        j0r[cb][lane] = (m >= 1.5f) ? (unsigned)j : 32u;   // 32 -> zero col
        if (lane < 32) {                // steps 64..95 (masked pass)
          const float* nvs2 = nv0r[cb] + 64 + lane;
          float m2 = nvs2[0];
          int j2 = 0;
#pragma unroll 8
          for (int n = 1; n < 32; ++n) {
            float v = nvs2[n * TS1];
            bool g = v > m2;
            j2 = g ? n : j2;
            m2 = g ? v : m2;
          }
          j0r[cb][64 + lane] = (m2 >= 1.5f) ? (unsigned)j2 : 32u;
        }
      }
    } else if (wid == 2) {
      // ---------- L1 update (chunk p-3): depth-8 gather rotation ----------
      const int c = p - 3;
      if (c >= 0 && c < NCHUNK) {
        const int S = min(CT, T_TOTAL - c * CT);
        const int cb = c & 1;
        const int jv  = (int)j0r[cb][lane];              // steps 0..63
        const int jv2 = (int)j0r[cb][64 + (lane & 31)];  // steps 64..95
        const float* wrow = w1s + lane * 33;
        float* nrow = nv1r[cb] + lane * TS1;
        float hr[8];
#pragma unroll
        for (int k = 0; k < 8; ++k) hr[k] = wrow[read_lane_i(jv, k)];
        for (int tb = 0; tb < S; tb += 8) {
          // blocks are 8-aligned: prefetch block never straddles step 64
          const int pb = tb + 8;
          const bool hi = pb >= 64;
          const int src = hi ? jv2 : jv;
          const int pbase = hi ? pb - 64 : pb;   // overruns read dup lanes: dead
          float nva[8];
#pragma unroll
          for (int k = 0; k < 8; ++k) {
            float h = hr[k];
            hr[k] = wrow[read_lane_i(src, pbase + k)];
            float a = nv1p + h;
            float m = nv1p * R80;
            bool  r = nv1p >= 1.2f;
            float f = a - m;
            nv1p = r ? h : f;
            nva[k] = nv1p;
          }
          f32x4 w0v = {nva[0], nva[1], nva[2], nva[3]};
          f32x4 w1v = {nva[4], nva[5], nva[6], nva[7]};
          *(f32x4*)(nrow + tb) = w0v;
          *(f32x4*)(nrow + tb + 4) = w1v;
        }
      }
    } else if (wid == 3 || wid == 6) {
      // ---------- L1 reduce (chunk p-4): lane = step, neuron half-scan ----
      const int c = p - 4;
      if (c >= 0 && c < NCHUNK) {
        const int cb = c & 1;
        const int half = (wid == 6) ? 1 : 0;
        const float* nvs = nv1r[cb] + half * 32 * TS1 + lane;
        float m = nvs[0];
        int j = 0;
#pragma unroll 8
        for (int n = 1; n < 32; ++n) {
          float v = nvs[n * TS1];
          bool g = v > m;
          j = g ? n : j;
          m = g ? v : m;
        }
        mpr[cb][half][lane] = m;
        jpr[cb][half][lane] = j;
        if (lane < 32) {                // steps 64..95 (masked pass)
          const float* nvs2 = nv1r[cb] + half * 32 * TS1 + 64 + lane;
          float m2 = nvs2[0];
          int j2 = 0;
#pragma unroll 8
          for (int n = 1; n < 32; ++n) {
            float v = nvs2[n * TS1];
            bool g = v > m2;
            j2 = g ? n : j2;
            m2 = g ? v : m2;
          }
          mpr[cb][half][64 + lane] = m2;
          jpr[cb][half][64 + lane] = j2;
        }
      }
    } else if (wid == 4) {
      // ---------- loader: x chunk p -> xs [ch][t], 12 dwordx4 ----------
      const int c = p;
      if (c < NCHUNK) {
        float* dst = xs[c & 1];
        const int g8 = lane >> 3;            // channel sub-index 0..7
        const int tl8 = (lane & 7) << 2;     // local t within 32-block
        f32x4 vr[12];
        bool okv[12];
        // Phase A: 12 independent 16B loads, back-to-back in flight.
#pragma unroll
        for (int j = 0; j < 12; ++j) {
          const int k = (j & 3) * 8 + g8;    // channel
          const int ts = j >> 2;             // t sub-block 0..2
          const int tg = c * CT + ts * 32 + tl8;
          const bool ok = (tg + 3) < T_TOTAL;
          okv[j] = ok;
          const int tgs = ok ? tg : 0;       // clamped, always in-bounds
          vr[j] = *reinterpret_cast<const f32x4*>(&xb[(size_t)k * T_TOTAL + tgs]);
        }
        // Phase B: 12 ds_write_b128 under exec mask; !ok rows stay stale,
        // only ever touched by L0u's dead prefetch (never consumed).
#pragma unroll
        for (int j = 0; j < 12; ++j) {
          if (okv[j]) {
            const int k = (j & 3) * 8 + g8;
            const int ts = j >> 2;
            *(f32x4*)(&dst[k * TS0 + ts * 32 + tl8]) = vr[j];
          }
        }
      }
    } else {
      // ---------- L2 update (chunk p-5): w5 rows 0-63, w7 rows 64-127 ----
      const int c = p - 5;
      if (c >= 0 && c < NCHUNK) {
        const int S = min(CT, T_TOTAL - c * CT);
        const int cb = c & 1;
        // merge L1 partials per-lane; tie -> low half = first index
        float mlo = mpr[cb][0][lane], mhi = mpr[cb][1][lane];
        int jlo = jpr[cb][0][lane], jhi = jpr[cb][1][lane];
        bool g = mhi > mlo;
        float mm = g ? mhi : mlo;
        int jj = g ? (jhi + 32) : jlo;
        const int pkv = (mm >= 1.2f) ? jj : 64;          // steps 0..63
        const int l32 = 64 + (lane & 31);
        float mlo2 = mpr[cb][0][l32], mhi2 = mpr[cb][1][l32];
        int jlo2 = jpr[cb][0][l32], jhi2 = jpr[cb][1][l32];
        bool g2 = mhi2 > mlo2;
        float mm2 = g2 ? mhi2 : mlo2;
        int jj2 = g2 ? (jhi2 + 32) : jlo2;
        const int pkv2 = (mm2 >= 1.2f) ? jj2 : 64;       // steps 64..95
        const float* wrow = w2s + (lane + ((wid == 7) ? 64 : 0)) * 65;
        float hr[8];
#pragma unroll
        for (int k = 0; k < 8; ++k) hr[k] = wrow[read_lane_i(pkv, k)];
        for (int tb = 0; tb < S; tb += 8) {
          const int pb = tb + 8;
          const bool hi = pb >= 64;
          const int src = hi ? pkv2 : pkv;
          const int pbase = hi ? pb - 64 : pb;
#pragma unroll
          for (int k = 0; k < 8; ++k) {
            float h = hr[k];
            hr[k] = wrow[read_lane_i(src, pbase + k)];
            float a = nv2p + h;
            float m = nv2p * R80;
            bool  r = nv2p >= 1.2f;
            float f = a - m;
            nv2p = r ? h : f;
          }
        }
      }
    }
    __syncthreads();  // wave-uniform branches: all 8 waves always arrive
  }

  // nv2p is the pre-reset membrane of the last step == pre_v2.
  if (wid == 5) out[(size_t)b * N2 + lane] = expf(nv2p);
  if (wid == 7) out[(size_t)b * N2 + 64 + lane] = expf(nv2p);
}

extern "C" void kernel_launch(void* const* d_in, const int* in_sizes, int n_in,
                              void* d_out, int out_size, void* d_ws, size_t ws_size,
                              hipStream_t stream) {
  (void)n_in; (void)out_size; (void)d_ws; (void)ws_size;
  const float* x = (const float*)d_in[0];
  const float* W1 = (const float*)d_in[1];
  const float* W2 = (const float*)d_in[2];
  float* out = (float*)d_out;
  const int B = in_sizes[0] / (NCH * T_TOTAL);  // 256
  lsm_kernel<<<dim3(B), dim3(512), 0, stream>>>(x, W1, W2, out);
}